// Round 10
// baseline (72.323 us; speedup 1.0000x reference)
//
#include <hip/hip_runtime.h>
#include <math.h>

typedef unsigned int uint32;
typedef unsigned short u16;
typedef __bf16 bf16x8 __attribute__((ext_vector_type(8)));
typedef float f32x16 __attribute__((ext_vector_type(16)));
typedef float f32x4  __attribute__((ext_vector_type(4)));

#define BROWS 8192
#define WDIM 256
#define NT 3              // tiles t0=(0,0), t1=(0,1), t2=(1,1)
#define CHUNKS 64         // 64 * 128 rows = 8192
#define RPB 128
#define TILE_ELEMS 16384
#define GRID_BLKS 64      // 64 fused-triple blocks x 512 threads

// ws layout (u16 view) — NO zeroing: every cell overwritten with coherent
// stores before any read.
// [0 .. 3145727]        gram partials bf16: ((c*NT)+t)*16384 + row*128 + col
// [3145728 .. 3162111]  colsum bf16 [c][256]
// f32 view: [1581056 .. 1581119] per-block loss [64]
#define WS_CSB_U16 (CHUNKS * NT * TILE_ELEMS)
#define WS_LOSS_F32 1581056

// Monotonic generation counters (device globals; ws is re-poisoned every
// iteration). +GRID_BLKS per launch; target = next multiple -> no reset
// needed across graph replays (proven rounds 3-8).
__device__ unsigned g_done = 0;
__device__ unsigned g_fin  = 0;

__device__ __forceinline__ uint32 pack2bf(float lo, float hi) {
    uint32 a = __float_as_uint(lo), b = __float_as_uint(hi);
    a = (a + 0x7FFFu + ((a >> 16) & 1u)) >> 16;   // RNE fp32->bf16
    b = (b + 0x7FFFu + ((b >> 16) & 1u)) >> 16;
    return (a & 0xFFFFu) | (b << 16);
}
__device__ __forceinline__ uint32 f2bf(float x) {
    uint32 a = __float_as_uint(x);
    return (a + 0x7FFFu + ((a >> 16) & 1u)) >> 16;
}
__device__ __forceinline__ float bflo(uint32 v) { return __uint_as_float(v << 16); }
__device__ __forceinline__ float bfhi(uint32 v) { return __uint_as_float(v & 0xFFFF0000u); }

// LDS: U[col][krp] (krp=k/2, 64 dwords/col), 16B-group XOR swizzle (proven).
__device__ __forceinline__ int uswz(int col, int krp) {
    return col * 64 + ((((krp >> 2) ^ (col & 15)) << 2) | (krp & 3));
}

__device__ __forceinline__ void aputf(float* p, float v) {
    __hip_atomic_store(p, v, __ATOMIC_RELAXED, __HIP_MEMORY_SCOPE_AGENT);
}
__device__ __forceinline__ void aput16(u16* p, uint32 v) {
    asm volatile("global_store_short %0, %1, off sc0 sc1"
                 :: "v"(p), "v"(v) : "memory");
}

// 8 coherent 16B loads in flight, one waitcnt (round-6/7-proven).
#define LD8(R0,R1,R2,R3,R4,R5,R6,R7,P0,P1,P2,P3,P4,P5,P6,P7)                 \
    asm volatile(                                                            \
        "global_load_dwordx4 %0, %8, off sc0 sc1\n\t"                        \
        "global_load_dwordx4 %1, %9, off sc0 sc1\n\t"                        \
        "global_load_dwordx4 %2, %10, off sc0 sc1\n\t"                       \
        "global_load_dwordx4 %3, %11, off sc0 sc1\n\t"                       \
        "global_load_dwordx4 %4, %12, off sc0 sc1\n\t"                       \
        "global_load_dwordx4 %5, %13, off sc0 sc1\n\t"                       \
        "global_load_dwordx4 %6, %14, off sc0 sc1\n\t"                       \
        "global_load_dwordx4 %7, %15, off sc0 sc1\n\t"                       \
        "s_waitcnt vmcnt(0)"                                                 \
        : "=&v"(R0),"=&v"(R1),"=&v"(R2),"=&v"(R3),                           \
          "=&v"(R4),"=&v"(R5),"=&v"(R6),"=&v"(R7)                            \
        : "v"(P0),"v"(P1),"v"(P2),"v"(P3),                                   \
          "v"(P4),"v"(P5),"v"(P6),"v"(P7))

#define LD1(R0,P0)                                                           \
    asm volatile("global_load_dwordx4 %0, %1, off sc0 sc1\n\t"               \
                 "s_waitcnt vmcnt(0)" : "=&v"(R0) : "v"(P0))

#define ACC8(S, V) do {                                                      \
    S[0] += bflo(V.x); S[1] += bfhi(V.x); S[2] += bflo(V.y); S[3] += bfhi(V.y);\
    S[4] += bflo(V.z); S[5] += bfhi(V.z); S[6] += bflo(V.w); S[7] += bfhi(V.w);\
} while (0)

__global__ __launch_bounds__(512)
void corr_v9(const float* __restrict__ E, float* __restrict__ ws,
             float* __restrict__ out) {
    __shared__ uint32 U[WDIM * 64];            // 64 KB: 256 cols x 128 rows bf16
    __shared__ float red[8];
    __shared__ int amFinal;
    const int c = blockIdx.x;
    const int tid = threadIdx.x;
    u16* part = (u16*)ws;

    // -------- phase A: read 128 E rows x 256 cols ONCE, cast to LDS --------
    // NON-TEMPORAL loads (nt): E has zero reuse after LDS staging, and the
    // IC/L2 are 100% dirty from the 256 MiB harness poison-fill. A normal
    // load miss must evict a dirty victim (writeback in the miss shadow);
    // nt skips allocation entirely -> raw-latency streaming reads.
    // (clang ext-vector f32x4, not HIP float4: the builtin rejects class types)
    const int row0 = c * RPB;
    const int c4 = tid & 15, rp = tid >> 4;    // rp 0..31

#define ISSUE(CG, FA, FB) do {                                                 \
    const float* Eb_ = E + (size_t)row0 * WDIM + (CG) * 64;                    \
    _Pragma("unroll")                                                          \
    for (int p = 0; p < 2; ++p) {                                              \
        const int r0_ = 2 * (rp + 32 * p);                                     \
        FA[p] = __builtin_nontemporal_load(                                    \
            (const f32x4*)(Eb_ + (size_t)r0_ * WDIM + c4 * 4));                \
        FB[p] = __builtin_nontemporal_load(                                    \
            (const f32x4*)(Eb_ + (size_t)(r0_ + 1) * WDIM + c4 * 4));          \
    }                                                                          \
} while (0)

#define WRITE(CG, FA, FB) do {                                                 \
    const int colb_ = (CG) * 64 + c4 * 4;                                      \
    _Pragma("unroll")                                                          \
    for (int p = 0; p < 2; ++p) {                                              \
        const int krp_ = rp + 32 * p;                                          \
        U[uswz(colb_ + 0, krp_)] = pack2bf(FA[p][0], FB[p][0]);                \
        U[uswz(colb_ + 1, krp_)] = pack2bf(FA[p][1], FB[p][1]);                \
        U[uswz(colb_ + 2, krp_)] = pack2bf(FA[p][2], FB[p][2]);                \
        U[uswz(colb_ + 3, krp_)] = pack2bf(FA[p][3], FB[p][3]);                \
    }                                                                          \
} while (0)

    f32x4 Afa[2], Afb[2], Bfa[2], Bfb[2];      // 2-deep prefetch (proven)
    ISSUE(0, Afa, Afb);
    for (int it = 0; it < 4; it += 2) {
        ISSUE(it + 1, Bfa, Bfb);
        WRITE(it, Afa, Afb);
        if (it + 2 < 4) ISSUE(it + 2, Afa, Afb);
        WRITE(it + 1, Bfa, Bfb);
    }
    __syncthreads();

    // colsum (every block holds all 256 cols of its 128 rows).
    float csum = 0.f;
    if (tid < 256) {
        #pragma unroll
        for (int g = 0; g < 16; ++g) {
            const uint4 v = *(const uint4*)&U[tid * 64 + ((g ^ (tid & 15)) << 2)];
            csum += bflo(v.x) + bfhi(v.x) + bflo(v.y) + bfhi(v.y)
                  + bflo(v.z) + bfhi(v.z) + bflo(v.w) + bfhi(v.w);
        }
    }

    // -------- MFMA: 8 waves, 6 acc tiles each --------
    // waves 0-3: t0[n=0..3] + t1[cols 0-63]  (rows 32w)
    // waves 4-7: t2[n=0..3] + t1[cols 64-127] (rows 32(w-4))
    const int w8 = tid >> 6, l = tid & 63, lm = l & 31;
    const int rg = w8 & 3;
    const bool hiW = (w8 >= 4);
    const int colA2 = rg * 32 + lm;                       // A lo (t0 / t1 rows)
    const int colA1 = (hiW ? 128 : 0) + rg * 32 + lm;     // main A (t0 or t2)
    const int bOff = hiW ? 128 : 0;                       // main tile B base
    const int t1n0 = hiW ? 2 : 0;                         // t1 n-offset

    f32x16 accA[4], accB[2];
    #pragma unroll
    for (int n = 0; n < 4; ++n)
        #pragma unroll
        for (int r = 0; r < 16; ++r) accA[n][r] = 0.f;
    #pragma unroll
    for (int m = 0; m < 2; ++m)
        #pragma unroll
        for (int r = 0; r < 16; ++r) accB[m][r] = 0.f;

#define FRAG(COL) (*(const bf16x8*)&U[(COL) * 64 + ((grp ^ ((COL) & 15)) << 2)])
    #pragma unroll
    for (int s8 = 0; s8 < 8; ++s8) {           // K = 128 rows, 8 steps of 16
        const int grp = 2 * s8 + (l >> 5);
        const bf16x8 aL = FRAG(colA2);
        bf16x8 aM;
        if (hiW) aM = FRAG(colA1); else aM = aL;   // wave-uniform branch
        #pragma unroll
        for (int n = 0; n < 4; ++n) {
            const bf16x8 b = FRAG(bOff + n * 32 + lm);
            accA[n] = __builtin_amdgcn_mfma_f32_32x32x16_bf16(aM, b, accA[n], 0, 0, 0);
        }
        #pragma unroll
        for (int m = 0; m < 2; ++m) {
            const bf16x8 b = FRAG(128 + (t1n0 + m) * 32 + lm);
            accB[m] = __builtin_amdgcn_mfma_f32_32x32x16_bf16(aL, b, accB[m], 0, 0, 0);
        }
    }

    // -------- publish bf16 partials (coherent fire-and-forget stores) -------
    // C/D layout (m74/m101): col = lane&31, row = (r&3)+8*(r>>2)+4*(lane>>5)
    const int tMain = hiW ? 2 : 0;
    u16* dstM = part + (size_t)(c * NT + tMain) * TILE_ELEMS;
    u16* dst1 = part + (size_t)(c * NT + 1) * TILE_ELEMS;
    const int rbase = 32 * rg + 4 * (l >> 5);
    #pragma unroll
    for (int n = 0; n < 4; ++n)
        #pragma unroll
        for (int r = 0; r < 16; ++r) {
            const int row = rbase + (r & 3) + 8 * (r >> 2);
            aput16(&dstM[row * 128 + n * 32 + lm], f2bf(accA[n][r]));
        }
    #pragma unroll
    for (int m = 0; m < 2; ++m)
        #pragma unroll
        for (int r = 0; r < 16; ++r) {
            const int row = rbase + (r & 3) + 8 * (r >> 2);
            aput16(&dst1[row * 128 + (t1n0 + m) * 32 + lm], f2bf(accB[m][r]));
        }
    if (tid < 256) aput16(&part[WS_CSB_U16 + c * WDIM + tid], f2bf(csum));

    // -------- fence-free grid barrier (64 arrivals; proven pattern) --------
    asm volatile("s_waitcnt vmcnt(0)" ::: "memory");
    __syncthreads();
    if (tid == 0) {
        const unsigned d = __hip_atomic_fetch_add(
            &g_done, 1u, __ATOMIC_RELAXED, __HIP_MEMORY_SCOPE_AGENT);
        const unsigned target = d - (d % GRID_BLKS) + GRID_BLKS;
        while (__hip_atomic_load(&g_done, __ATOMIC_RELAXED,
                                 __HIP_MEMORY_SCOPE_AGENT) < target)
            __builtin_amdgcn_s_sleep(4);
    }
    __syncthreads();

    // -------- distributed tail: block c -> 768 outputs (256 per tile) ------
    float* muS   = (float*)U;                  // [256]
    float* redm  = (float*)U + 256;            // [8][256]
    float* redgA = (float*)U + 2304;           // [8][256]
    float* redgB = (float*)U + 4352;           // [8][256]
    const int local0 = c * 256;

    // mu partial sums (tid<256), colsum slices batched (R7 m-pattern)
    if (tid < 256) {
        const int l2 = tid & 63, w2 = tid >> 6, h2 = l2 >> 5, q2 = l2 & 31;
        const int cc0 = w2 * 16 + h2 * 8, grpi = w2 * 2 + h2;
        const u16* baseM = part + WS_CSB_U16 + 8 * q2;
        uint4 m0, m1, m2, m3, m4, m5, m6, m7;
        LD8(m0, m1, m2, m3, m4, m5, m6, m7,
            (const uint4*)(baseM + (cc0 + 0) * WDIM),
            (const uint4*)(baseM + (cc0 + 1) * WDIM),
            (const uint4*)(baseM + (cc0 + 2) * WDIM),
            (const uint4*)(baseM + (cc0 + 3) * WDIM),
            (const uint4*)(baseM + (cc0 + 4) * WDIM),
            (const uint4*)(baseM + (cc0 + 5) * WDIM),
            (const uint4*)(baseM + (cc0 + 6) * WDIM),
            (const uint4*)(baseM + (cc0 + 7) * WDIM));
        float ms[8] = {0,0,0,0,0,0,0,0};
        ACC8(ms, m0); ACC8(ms, m1); ACC8(ms, m2); ACC8(ms, m3);
        ACC8(ms, m4); ACC8(ms, m5); ACC8(ms, m6); ACC8(ms, m7);
        #pragma unroll
        for (int j2 = 0; j2 < 8; ++j2) redm[grpi * 256 + 8 * q2 + j2] = ms[j2];
    }

    // gram pass 1: half h handles region tt=h (R7 g-pattern per 256 threads)
    const int hh = tid >> 8, tl = tid & 255;
    const int l3 = tl & 63, w3 = tl >> 6, h3 = l3 >> 5, q3 = l3 & 31;
    const int cc0g = w3 * 16 + h3 * 8, grpg = w3 * 2 + h3;
    {
        const u16* baseG = part + (size_t)hh * TILE_ELEMS + local0 + 8 * q3;
        uint4 g0, g1, g2, g3, g4, g5, g6, g7;
        LD8(g0, g1, g2, g3, g4, g5, g6, g7,
            (const uint4*)(baseG + (size_t)(cc0g + 0) * (NT * TILE_ELEMS)),
            (const uint4*)(baseG + (size_t)(cc0g + 1) * (NT * TILE_ELEMS)),
            (const uint4*)(baseG + (size_t)(cc0g + 2) * (NT * TILE_ELEMS)),
            (const uint4*)(baseG + (size_t)(cc0g + 3) * (NT * TILE_ELEMS)),
            (const uint4*)(baseG + (size_t)(cc0g + 4) * (NT * TILE_ELEMS)),
            (const uint4*)(baseG + (size_t)(cc0g + 5) * (NT * TILE_ELEMS)),
            (const uint4*)(baseG + (size_t)(cc0g + 6) * (NT * TILE_ELEMS)),
            (const uint4*)(baseG + (size_t)(cc0g + 7) * (NT * TILE_ELEMS)));
        float gs[8] = {0,0,0,0,0,0,0,0};
        ACC8(gs, g0); ACC8(gs, g1); ACC8(gs, g2); ACC8(gs, g3);
        ACC8(gs, g4); ACC8(gs, g5); ACC8(gs, g6); ACC8(gs, g7);
        float* rgp = hh ? redgB : redgA;
        #pragma unroll
        for (int j2 = 0; j2 < 8; ++j2) rgp[grpg * 256 + 8 * q3 + j2] = gs[j2];
    }
    __syncthreads();
    if (tid < 256) {
        float s = 0.f;
        #pragma unroll
        for (int gg = 0; gg < 8; ++gg) s += redm[gg * 256 + tid];
        muS[tid] = s * (1.0f / (float)BROWS);
    }
    __syncthreads();

    float v = 0.f;
    {   // finalize pass-1 output (tt=hh, local = local0+tl)
        const float* rgp = hh ? redgB : redgA;
        float gsum = 0.f;
        #pragma unroll
        for (int gg = 0; gg < 8; ++gg) gsum += rgp[gg * 256 + tl];
        const int local = local0 + tl;
        const int i = (local >> 7);                        // tt=0/1: i in [0,128)
        const int j = ((hh == 0) ? 0 : 128) + (local & 127);
        const float diff = gsum * (1.0f / (float)BROWS) - muS[i] * muS[j]
                         - ((i == j) ? 1.0f : 0.0f);
        v += ((hh == 1) ? 2.0f : 1.0f) * diff * diff;
    }
    __syncthreads();                            // redgA free for pass 2

    // gram pass 2: tt=2 by tid<256
    if (tid < 256) {
        const u16* baseG = part + (size_t)2 * TILE_ELEMS + local0 + 8 * q3;
        uint4 g0, g1, g2, g3, g4, g5, g6, g7;
        LD8(g0, g1, g2, g3, g4, g5, g6, g7,
            (const uint4*)(baseG + (size_t)(cc0g + 0) * (NT * TILE_ELEMS)),
            (const uint4*)(baseG + (size_t)(cc0g + 1) * (NT * TILE_ELEMS)),
            (const uint4*)(baseG + (size_t)(cc0g + 2) * (NT * TILE_ELEMS)),
            (const uint4*)(baseG + (size_t)(cc0g + 3) * (NT * TILE_ELEMS)),
            (const uint4*)(baseG + (size_t)(cc0g + 4) * (NT * TILE_ELEMS)),
            (const uint4*)(baseG + (size_t)(cc0g + 5) * (NT * TILE_ELEMS)),
            (const uint4*)(baseG + (size_t)(cc0g + 6) * (NT * TILE_ELEMS)),
            (const uint4*)(baseG + (size_t)(cc0g + 7) * (NT * TILE_ELEMS)));
        float gs[8] = {0,0,0,0,0,0,0,0};
        ACC8(gs, g0); ACC8(gs, g1); ACC8(gs, g2); ACC8(gs, g3);
        ACC8(gs, g4); ACC8(gs, g5); ACC8(gs, g6); ACC8(gs, g7);
        #pragma unroll
        for (int j2 = 0; j2 < 8; ++j2) redgA[grpg * 256 + 8 * q3 + j2] = gs[j2];
    }
    __syncthreads();
    if (tid < 256) {
        float gsum = 0.f;
        #pragma unroll
        for (int gg = 0; gg < 8; ++gg) gsum += redgA[gg * 256 + tid];
        const int local = local0 + tid;
        const int i = 128 + (local >> 7);
        const int j = 128 + (local & 127);
        const float diff = gsum * (1.0f / (float)BROWS) - muS[i] * muS[j]
                         - ((i == j) ? 1.0f : 0.0f);
        v += diff * diff;
    }

    // block reduce (8 waves) -> per-block loss slot
    #pragma unroll
    for (int o = 32; o > 0; o >>= 1) v += __shfl_down(v, o, 64);
    if ((tid & 63) == 0) red[tid >> 6] = v;
    __syncthreads();
    float* lossp = ws + WS_LOSS_F32;
    if (tid == 0) {
        float bl = 0.f;
        #pragma unroll
        for (int k = 0; k < 8; ++k) bl += red[k];
        aputf(&lossp[c], bl);
    }
    asm volatile("s_waitcnt vmcnt(0)" ::: "memory");
    __syncthreads();
    if (tid == 0) {
        const unsigned d2 = __hip_atomic_fetch_add(
            &g_fin, 1u, __ATOMIC_RELAXED, __HIP_MEMORY_SCOPE_AGENT);
        amFinal = ((d2 % GRID_BLKS) == GRID_BLKS - 1);
    }
    __syncthreads();
    if (!amFinal) return;                      // 63 blocks exit immediately

    // final gather: 16 lanes x one dwordx4 over 64 per-block losses
    f32x4 lv4 = {0.f, 0.f, 0.f, 0.f};
    if (tid < 16) LD1(lv4, (const f32x4*)(lossp + 4 * tid));
    if (tid < 64) {
        float lv = lv4[0] + lv4[1] + lv4[2] + lv4[3];
        #pragma unroll
        for (int o = 32; o > 0; o >>= 1) lv += __shfl_down(lv, o, 64);
        if (tid == 0) out[0] = sqrtf(lv);
    }
}

// ---------------------------------------------------------------------- host
extern "C" void kernel_launch(void* const* d_in, const int* in_sizes, int n_in,
                              void* d_out, int out_size, void* d_ws, size_t ws_size,
                              hipStream_t stream) {
    const float* E = (const float*)d_in[0];
    // d_in[1] (label) unused by the reference math.
    float* out = (float*)d_out;
    float* ws = (float*)d_ws;

    corr_v9<<<dim3(GRID_BLKS), 512, 0, stream>>>(E, ws, out);
}